// Round 1
// 2825.365 us; speedup vs baseline: 1.0386x; 1.0386x over previous
//
#include <hip/hip_runtime.h>
#include <cstdint>
#include <cstddef>

#define TT   512
#define BATCH 64
#define HID  1024
#define KDIM 1024

typedef short bf16x8 __attribute__((ext_vector_type(8)));
typedef float f32x4 __attribute__((ext_vector_type(4)));

__device__ __forceinline__ unsigned short f2b(float f) {
    unsigned int u = __float_as_uint(f);
    u = (u + 0x7fffu + ((u >> 16) & 1u)) >> 16;
    return (unsigned short)u;
}

// ---------------------------------------------------------------------------
// init: concat biases, zero h buffers + flags
// ---------------------------------------------------------------------------
__global__ __launch_bounds__(256) void k_init(
    const float* __restrict__ b_ir, const float* __restrict__ b_iz, const float* __restrict__ b_in,
    const float* __restrict__ b_hr, const float* __restrict__ b_hz, const float* __restrict__ b_hn,
    float* __restrict__ bias_x, float* __restrict__ bias_h,
    unsigned short* __restrict__ hbf, int* __restrict__ flags)
{
    int gid = blockIdx.x * 256 + threadIdx.x;          // grid 64x256 = 16384
    if (gid < HID) {
        bias_x[gid]        = b_ir[gid];
        bias_x[HID + gid]  = b_iz[gid];
        bias_x[2*HID + gid]= b_in[gid];
        bias_h[gid]        = b_hr[gid];
        bias_h[HID + gid]  = b_hz[gid];
        bias_h[2*HID + gid]= b_hn[gid];
    }
    // zero both h bf16 buffers: 2*64*1024 ushorts = 32768 ushort4
    ushort4 z4 = make_ushort4(0, 0, 0, 0);
    ushort4* p = reinterpret_cast<ushort4*>(hbf);
    p[2*gid]   = z4;
    p[2*gid+1] = z4;
    if (gid < 256 * 16) flags[gid] = 0;                // 256 flags, 64B-padded
}

// ---------------------------------------------------------------------------
// transpose W[k][j] (fp32) -> wT[n][k] (bf16), n = gate*1024 + j
// grid (32, 32, 6), block (32, 8)
// ---------------------------------------------------------------------------
__global__ __launch_bounds__(256) void k_trans(
    const float* __restrict__ w0, const float* __restrict__ w1, const float* __restrict__ w2,
    const float* __restrict__ w3, const float* __restrict__ w4, const float* __restrict__ w5,
    unsigned short* __restrict__ wxT, unsigned short* __restrict__ whT)
{
    __shared__ float tile[32][33];
    int z = blockIdx.z;
    const float* src = (z == 0) ? w0 : (z == 1) ? w1 : (z == 2) ? w2
                     : (z == 3) ? w3 : (z == 4) ? w4 : w5;
    unsigned short* dst = (z < 3) ? (wxT + (size_t)z * HID * KDIM)
                                  : (whT + (size_t)(z - 3) * HID * KDIM);
    int kb = blockIdx.x * 32, jb = blockIdx.y * 32;
    int tx = threadIdx.x, ty = threadIdx.y;
    #pragma unroll
    for (int p = 0; p < 4; p++)
        tile[tx][ty + 8*p] = src[(size_t)(kb + ty + 8*p) * HID + jb + tx];
    __syncthreads();
    #pragma unroll
    for (int p = 0; p < 4; p++) {
        int n = jb + ty + 8*p;
        dst[(size_t)n * KDIM + kb + tx] = f2b(tile[ty + 8*p][tx]);
    }
}

// ---------------------------------------------------------------------------
// GEMM A: gates = x @ [W_ir|W_iz|W_in] + bias.  M=32768, N=3072, K=1024.
// ---------------------------------------------------------------------------
#define BM 128
#define BN 128
#define LDA 72   // 64 + 8 pad, in ushorts (144 B rows, 16B-aligned)

__global__ __launch_bounds__(256, 2) void k_gemm_x(
    const float* __restrict__ x,            // [32768][1024] fp32
    const unsigned short* __restrict__ wxT, // [3072][1024] bf16
    const float* __restrict__ biasx,        // [3072]
    float* __restrict__ ggr, float* __restrict__ ggz, float* __restrict__ ggn)
{
    __shared__ unsigned short lA[BM * LDA];
    __shared__ unsigned short lB[BN * LDA];
    int tid  = threadIdx.x;
    int wave = tid >> 6, lane = tid & 63;
    int l16  = lane & 15, lhi = lane >> 4;
    int rbase = blockIdx.x * BM;
    int nbase = blockIdx.y * BN;
    int wm = (wave >> 1) * 64, wn = (wave & 1) * 64;

    f32x4 acc[4][4];
    for (int a = 0; a < 4; a++)
        for (int b = 0; b < 4; b++)
            acc[a][b] = f32x4{0.f, 0.f, 0.f, 0.f};

    int arow = tid >> 4;          // 16 rows/pass, 8 passes
    int acol = (tid & 15) * 4;    // float4 within 64 floats
    int brow = tid >> 3;          // 32 rows/pass, 4 passes
    int bcol = (tid & 7) * 8;     // 8 shorts within 64

    for (int kb = 0; kb < KDIM; kb += 64) {
        __syncthreads();
        #pragma unroll
        for (int p = 0; p < 8; p++) {
            int r = p * 16 + arow;
            float4 v = *(const float4*)(x + (size_t)(rbase + r) * KDIM + kb + acol);
            ushort4 s;
            s.x = f2b(v.x); s.y = f2b(v.y); s.z = f2b(v.z); s.w = f2b(v.w);
            *(ushort4*)(lA + r * LDA + acol) = s;
        }
        #pragma unroll
        for (int p = 0; p < 4; p++) {
            int r = p * 32 + brow;
            bf16x8 v = *(const bf16x8*)(wxT + (size_t)(nbase + r) * KDIM + kb + bcol);
            *(bf16x8*)(lB + r * LDA + bcol) = v;
        }
        __syncthreads();
        #pragma unroll
        for (int kk = 0; kk < 2; kk++) {
            bf16x8 af[4], bfr[4];
            #pragma unroll
            for (int mt = 0; mt < 4; mt++)
                af[mt] = *(const bf16x8*)(lA + (wm + mt*16 + l16) * LDA + kk*32 + lhi*8);
            #pragma unroll
            for (int nt = 0; nt < 4; nt++)
                bfr[nt] = *(const bf16x8*)(lB + (wn + nt*16 + l16) * LDA + kk*32 + lhi*8);
            #pragma unroll
            for (int mt = 0; mt < 4; mt++)
                #pragma unroll
                for (int nt = 0; nt < 4; nt++)
                    acc[mt][nt] = __builtin_amdgcn_mfma_f32_16x16x32_bf16(
                        af[mt], bfr[nt], acc[mt][nt], 0, 0, 0);
        }
    }
    // epilogue: C/D layout col=lane&15 (N), row=(lane>>4)*4+i (M)
    #pragma unroll
    for (int nt = 0; nt < 4; nt++) {
        int n = nbase + wn + nt*16 + l16;
        float bv = biasx[n];
        int g = n >> 10;
        int j = n & 1023;
        float* outp = (g == 0) ? ggr : (g == 1) ? ggz : ggn;
        #pragma unroll
        for (int mt = 0; mt < 4; mt++) {
            #pragma unroll
            for (int i = 0; i < 4; i++) {
                int R = rbase + wm + mt*16 + lhi*4 + i;        // R = b*512 + t
                size_t orow = (size_t)((R & 511) * BATCH + (R >> 9));
                outp[orow * HID + j] = acc[mt][nt][i] + bv;
            }
        }
    }
}

// ---------------------------------------------------------------------------
// Recurrence: persistent, 256 blocks x 256 thr (1 block/CU on all 256 CUs).
// Block = 16 cols (c=blk>>2) x 16 batch rows (q=blk&3). Waves split K
// (256 each); weights register-resident (24 bf16x8/lane). LDS reduce; one
// output element per thread.
//
// Sync v2 (this round):
//  - Wave w polls ONLY its 16 K-quarter producers (blocks (q, c'∈[16w,16w+16))),
//    all 64 lanes read the l16-replicated flag address -> the wave's poll
//    coalesces to 16 LLC requests/round (was 256 uncoalesced), and each wave
//    releases as soon as ITS producers are done (no global straggler coupling).
//  - Publish: hsu-pack barrier retained, but the trailing full-block barrier is
//    replaced by a wave-0-local s_waitcnt vmcnt(0) before the flag store;
//    waves 1-3 immediately proceed to the next step's poll.
// LDS hazards: 'red' reads (step t) happen before the hsu-pack barrier; 'red'
// writes (step t+1) happen after it. 'hsu' reads (wave 0, step t) happen
// before wave 0 joins the step-t+1 reduce barrier; 'hsu' writes (t+1) after.
// ---------------------------------------------------------------------------
__global__ __launch_bounds__(256, 1) void k_recur(
    const float* __restrict__ ggr, const float* __restrict__ ggz,
    float* __restrict__ dout,                // [T][B][H] (gn preloaded) + tail [B][H]
    const unsigned short* __restrict__ whT,  // [3072][1024] bf16
    const float* __restrict__ biash,         // [3072]
    unsigned short* __restrict__ hbf,        // [2][64][1024] bf16
    int* __restrict__ flags)                 // [256] stride-16 ints (64 B lines)
{
    __shared__ float red[3 * 4 * 64 * 4];        // 12 KB: gate, wave, lane, reg
    __shared__ unsigned long long hsu[64];       // 512 B: 16x16 bf16 h tile
    unsigned short* hsp = (unsigned short*)hsu;

    int tid  = threadIdx.x;
    int w    = tid >> 6, lane = tid & 63;
    int l16  = lane & 15, lhi = lane >> 4;
    int blk  = blockIdx.x;
    int q    = blk & 3;            // batch quarter (rows q*16 .. q*16+15)
    int c    = blk >> 2;           // column group (cols c*16 .. c*16+15)
    int row  = tid >> 4;           // epilogue row 0..15
    int col  = tid & 15;           // epilogue col 0..15
    int j_l  = c * 16 + l16;       // mfma lane's column
    int j_t  = c * 16 + col;       // epilogue thread's column
    int b_t  = q * 16 + row;       // epilogue thread's batch row
    int kbase = w * 256 + lhi * 8; // this lane's K base

    // this wave's K-quarter producer flag: block (q, c' = w*16 + l16)
    int* myflag = &flags[((w * 16 + l16) * 4 + q) * 16];

    // loop-invariant weight fragments -> registers (24 x bf16x8 = 96 VGPR)
    bf16x8 wr[8], wz[8], wn[8];
    {
        const unsigned short* base = whT + (size_t)j_l * KDIM + kbase;
        #pragma unroll
        for (int kk = 0; kk < 8; kk++) {
            wr[kk] = *(const bf16x8*)(base + kk*32);
            wz[kk] = *(const bf16x8*)(base + kk*32 + (size_t)HID * KDIM);
            wn[kk] = *(const bf16x8*)(base + kk*32 + (size_t)2 * HID * KDIM);
        }
    }
    float bhr = biash[j_t], bhz = biash[HID + j_t], bhn = biash[2*HID + j_t];

    float hp = 0.f;
    float cgr, cgz, cgn;
    {
        size_t g0 = (size_t)b_t * HID + j_t;    // t = 0
        cgr = ggr[g0]; cgz = ggz[g0]; cgn = dout[g0];
    }

    #pragma unroll 1
    for (int t = 0; t < TT; t++) {
        // ---- wait for step-t h from THIS wave's 16 producers only ----
        if (t > 0) {
            bool ok;
            do {
                int f = __hip_atomic_load(myflag, __ATOMIC_RELAXED, __HIP_MEMORY_SCOPE_AGENT);
                ok = (f >= t);
            } while (!__all(ok));
        }

        // ---- h fragment loads: 16 rows x this wave's K-quarter, sc1 (LLC) ----
        const unsigned short* hb = hbf + (size_t)(t & 1) * BATCH * HID
                                 + (size_t)(q * 16 + l16) * HID + kbase;
        unsigned long long hu[16];
        #pragma unroll
        for (int kk = 0; kk < 8; kk++) {
            hu[2*kk]   = __hip_atomic_load((unsigned long long*)(hb + kk*32),
                                           __ATOMIC_RELAXED, __HIP_MEMORY_SCOPE_AGENT);
            hu[2*kk+1] = __hip_atomic_load((unsigned long long*)(hb + kk*32) + 1,
                                           __ATOMIC_RELAXED, __HIP_MEMORY_SCOPE_AGENT);
        }

        // ---- gate prefetch for t+1 (plain cached loads, lands during MFMA) ----
        float ngr = 0.f, ngz = 0.f, ngn = 0.f;
        if (t + 1 < TT) {
            size_t g1 = (size_t)((t + 1) * BATCH + b_t) * HID + j_t;
            ngr = ggr[g1]; ngz = ggz[g1]; ngn = dout[g1];
        }

        // ---- partial GEMM over this wave's K-quarter (m=1 tile, 3 gates) ----
        f32x4 a0{0.f,0.f,0.f,0.f}, a1{0.f,0.f,0.f,0.f}, a2{0.f,0.f,0.f,0.f};
        #pragma unroll
        for (int kk = 0; kk < 8; kk++) {
            union { unsigned long long u[2]; bf16x8 v; } fa;
            fa.u[0] = hu[2*kk]; fa.u[1] = hu[2*kk+1];
            a0 = __builtin_amdgcn_mfma_f32_16x16x32_bf16(fa.v, wr[kk], a0, 0, 0, 0);
            a1 = __builtin_amdgcn_mfma_f32_16x16x32_bf16(fa.v, wz[kk], a1, 0, 0, 0);
            a2 = __builtin_amdgcn_mfma_f32_16x16x32_bf16(fa.v, wn[kk], a2, 0, 0, 0);
        }

        // ---- cross-wave K reduction via LDS ----
        {
            f32x4* rp = (f32x4*)red;
            rp[(0*4 + w) * 64 + lane] = a0;
            rp[(1*4 + w) * 64 + lane] = a1;
            rp[(2*4 + w) * 64 + lane] = a2;
        }
        __syncthreads();
        int lsrc = (row >> 2) * 16 + col, ri = row & 3;
        float s0 = 0.f, s1 = 0.f, s2 = 0.f;
        #pragma unroll
        for (int ww = 0; ww < 4; ww++) {
            s0 += red[((0*4 + ww) * 64 + lsrc) * 4 + ri];
            s1 += red[((1*4 + ww) * 64 + lsrc) * 4 + ri];
            s2 += red[((2*4 + ww) * 64 + lsrc) * 4 + ri];
        }

        // ---- epilogue: one element per thread ----
        float r  = 1.f / (1.f + __expf(-(cgr + s0 + bhr)));
        float z  = 1.f / (1.f + __expf(-(cgz + s1 + bhz)));
        float nv = cgn + r * (s2 + bhn);
        float th = 1.f - 2.f / (1.f + __expf(2.f * nv));   // tanh(nv)
        float hv = (1.f - z) * th + z * hp;
        hp = hv;
        dout[((size_t)t * BATCH + b_t) * HID + j_t] = hv;  // plain store (private)
        if (t == TT - 1) {
            dout[(size_t)TT * BATCH * HID + (size_t)b_t * HID + j_t] = hv;
            break;                                         // no one consumes next h
        }
        cgr = ngr; cgz = ngz; cgn = ngn;

        // ---- publish h tile: LDS pack -> 64 x 8B write-through stores ----
        hsp[row * 16 + col] = f2b(hv);
        __syncthreads();
        if (tid < 64) {
            int rr = tid >> 2, ch = tid & 3;
            unsigned long long v = hsu[rr * 4 + ch];
            unsigned long long* dst = (unsigned long long*)(
                hbf + (size_t)((t + 1) & 1) * BATCH * HID
                    + (size_t)(q * 16 + rr) * HID + c * 16 + ch * 4);
            __hip_atomic_store(dst, v, __ATOMIC_RELAXED, __HIP_MEMORY_SCOPE_AGENT);
            // drain h stores at LLC (wave-0-local), then release consumers
            asm volatile("s_waitcnt vmcnt(0)" ::: "memory");
            if (tid == 0)
                __hip_atomic_store(&flags[blk * 16], t + 1,
                                   __ATOMIC_RELAXED, __HIP_MEMORY_SCOPE_AGENT);
        }
        // no trailing barrier: waves 1-3 are already polling for step t+1
    }
}

// ---------------------------------------------------------------------------
extern "C" void kernel_launch(void* const* d_in, const int* in_sizes, int n_in,
                              void* d_out, int out_size, void* d_ws, size_t ws_size,
                              hipStream_t stream)
{
    const float* x    = (const float*)d_in[0];
    const float* W_ir = (const float*)d_in[1];
    const float* b_ir = (const float*)d_in[2];
    const float* W_hr = (const float*)d_in[3];
    const float* b_hr = (const float*)d_in[4];
    const float* W_iz = (const float*)d_in[5];
    const float* b_iz = (const float*)d_in[6];
    const float* W_hz = (const float*)d_in[7];
    const float* b_hz = (const float*)d_in[8];
    const float* W_in = (const float*)d_in[9];
    const float* b_in = (const float*)d_in[10];
    const float* W_hn = (const float*)d_in[11];
    const float* b_hn = (const float*)d_in[12];
    float* out = (float*)d_out;

    char* ws = (char*)d_ws;
    size_t off = 0;
    auto alloc = [&](size_t bytes) -> char* {
        char* p = ws + off;
        off += (bytes + 255) & ~(size_t)255;
        return p;
    };
    float*          ggr      = (float*)alloc((size_t)TT * BATCH * HID * 4);
    float*          ggz      = (float*)alloc((size_t)TT * BATCH * HID * 4);
    unsigned short* wxT      = (unsigned short*)alloc((size_t)3 * HID * KDIM * 2);
    unsigned short* whT      = (unsigned short*)alloc((size_t)3 * HID * KDIM * 2);
    float*          bias_x   = (float*)alloc(3 * HID * 4);
    float*          bias_h   = (float*)alloc(3 * HID * 4);
    unsigned short* hbf      = (unsigned short*)alloc((size_t)2 * BATCH * HID * 2);
    int*            flags    = (int*)alloc(256 * 16 * 4);

    k_init<<<64, 256, 0, stream>>>(b_ir, b_iz, b_in, b_hr, b_hz, b_hn,
                                   bias_x, bias_h, hbf, flags);
    k_trans<<<dim3(32, 32, 6), dim3(32, 8), 0, stream>>>(W_ir, W_iz, W_in,
                                                         W_hr, W_hz, W_hn, wxT, whT);
    k_gemm_x<<<dim3(256, 24), 256, 0, stream>>>(x, wxT, bias_x, ggr, ggz, out);
    k_recur<<<256, 256, 0, stream>>>(ggr, ggz, out, whT, bias_h, hbf, flags);
}